// Round 7
// baseline (288.228 us; speedup 1.0000x reference)
//
#include <hip/hip_runtime.h>

// QAttentionLayer: out[..., i] = prod_{j<=i} cos(x_j)*cos(w_j), rows of 10 fp32.
// App traffic 335.5 MB; HBM-side ~244 MB (L3 absorbs ~half the fetch).
//
// Ledger (bench ~= ~186-205 us harness fills + kernel):
//   R0 scalar LDS + conflicts + barriers      kernel ~97 us
//   R2 b128 LDS + gll DMA + barriers          kernel ~96 us
//   R5 wave-autonomous zero-barrier LDS       kernel ~95 us
//   R4/R6 persistent pipelined (counted vmcnt) kernel ~101 us
//   R3b no-LDS + NONTEMPORAL stores           kernel 313 us, WRITE 3.4x ideal
// Five disjoint schedules pin at 95-101 us = 3.5 TB/s app-side, while pure-write
// fills hit 6.6 TB/s in the same iteration. All LDS/barrier/dispatch theories
// exonerated.
//
// R7: the one untested structure -- PURE-REGISTER row-pair kernel with CACHED
// stores. R3b's 3.4x write amplification is theorized nt-CAUSED, not
// stride-caused: 80B-lane-stride stores put one 16B fragment per 64B line per
// instruction; line completion requires L2 write-allocate merging across the 5
// stores, which the nt (no-allocate/evict) hint defeats. Loads never amplified
// (R3b FETCH 97 MB, normal). Dropping nt restores L2 merging -> full-line
// writebacks. Zero serialization: 5 independent loads -> 40 VALU -> 5 stores,
// no LDS, no DMA, no barriers, ~28 VGPR, max occupancy.
//
// 3-way prediction:
//  (1) WRITE ~164 MB, kernel copy-like 55-75 us -> bench ~245-265  [win]
//  (2) WRITE ~550 MB again -> stride-stores inherently amplify -> LDS ceiling
//      at 95 us is structural -> roofline
//  (3) WRITE ~164 MB but kernel ~95 us -> mixed-R/W memory-system invariant ->
//      roofline

#define BLOCK 256
#define NQ 10

typedef float f32x4 __attribute__((ext_vector_type(4)));

__global__ __launch_bounds__(BLOCK) void qcircuit_kernel(
    const float* __restrict__ x,
    const float* __restrict__ w,
    float* __restrict__ out,
    long long n_rows)
{
    const long long n_pairs = n_rows >> 1;
    const long long p = (long long)blockIdx.x * BLOCK + threadIdx.x;

    // cos(weights): uniform scalar loads
    float cw[NQ];
    #pragma unroll
    for (int j = 0; j < NQ; ++j) cw[j] = __cosf(w[j]);

    if (p < n_pairs) {
        const f32x4* __restrict__ gin  = (const f32x4*)x + p * 5;
        f32x4* __restrict__       gout = (f32x4*)out     + p * 5;

        float v[20];                         // static indexing -> stays in VGPRs
        f32x4* vr = (f32x4*)v;
        #pragma unroll
        for (int k = 0; k < 5; ++k) vr[k] = gin[k];   // 5 independent loads in flight

        float pr = 1.0f;
        #pragma unroll
        for (int j = 0; j < NQ; ++j) { pr *= __cosf(v[j]) * cw[j]; v[j] = pr; }
        pr = 1.0f;
        #pragma unroll
        for (int j = 0; j < NQ; ++j) { pr *= __cosf(v[NQ + j]) * cw[j]; v[NQ + j] = pr; }

        #pragma unroll
        for (int k = 0; k < 5; ++k) gout[k] = vr[k];  // cached: L2 merges lines
    } else if ((n_rows & 1) && p == n_pairs) {
        // odd tail row (not hit at bench shape): scalar in-place
        const float* gi = x   + 2 * n_pairs * NQ;
        float*       go = out + 2 * n_pairs * NQ;
        float pr = 1.0f;
        #pragma unroll
        for (int j = 0; j < NQ; ++j) { pr *= __cosf(gi[j]) * cw[j]; go[j] = pr; }
    }
}

extern "C" void kernel_launch(void* const* d_in, const int* in_sizes, int n_in,
                              void* d_out, int out_size, void* d_ws, size_t ws_size,
                              hipStream_t stream) {
    const float* x = (const float*)d_in[0];
    const float* w = (const float*)d_in[1];
    float* out = (float*)d_out;

    const long long n_elem = in_sizes[0];
    const long long n_rows = n_elem / NQ;
    const long long n_work = (n_rows >> 1) + (n_rows & 1);   // pairs + tail row
    const int blocks = (int)((n_work + BLOCK - 1) / BLOCK);

    hipLaunchKernelGGL(qcircuit_kernel, dim3(blocks), dim3(BLOCK), 0, stream,
                       x, w, out, n_rows);
}

// Round 8
// 282.784 us; speedup vs baseline: 1.0193x; 1.0193x over previous
//
#include <hip/hip_runtime.h>

// QAttentionLayer: out[..., i] = prod_{j<=i} cos(x_j)*cos(w_j), rows of 10 fp32.
// App traffic 335.5 MB; HBM-side ~246 MB (L3 half-serves reads).
//
// FINAL LEDGER (bench = ~186.5 us harness re-poison fills + kernel):
//   R0 scalar LDS + 4-way conflicts + barriers   ~97 us
//   R2 b128 LDS + gll DMA + barriers             ~96 us
//   R5 wave-autonomous, zero barriers  [BEST]    ~94.6 us   <- this kernel
//   R4 persistent dbuf, 16 w/CU, nt stores       ~101 us
//   R6 persistent, counted-vmcnt prefetch        ~101 us
//   R7 pure-register, cached stores (profiled)    101.2 us, WRITE ideal,
//      occupancy 73%, VALU 7%, 2.55 TB/s HBM-side
// Six disjoint schedules within +-3.5%: bank conflicts, staging style,
// barriers, persistence, pipeline depth, store policy, occupancy all
// exonerated. All on-CU counters slack. Limiter = memory-system service
// rate for this balanced R+W pattern (platform-level, unschedulable).
// R3b lesson: nontemporal + partial-line (80B-stride) stores = 3.4x write
// amplification; full-line or cached stores are mandatory.
//
// R8 = exact resubmission of R5 (the measured best) to end the session on
// the best kernel and test reproducibility of 94.6 vs the 98+-3 band.
// Predicted: bench 281-285, kernel out of top-5, fills ~100.5 us unchanged.

#define BLOCK 256
#define WAVES 4
#define NQ 10
#define WQ 320                    // f32x4 per wave-tile = 5 KiB = 128 rows
#define ROWS_PER_WAVE 128

typedef float f32x4 __attribute__((ext_vector_type(4)));

__global__ __launch_bounds__(BLOCK) void qcircuit_kernel(
    const float* __restrict__ x,
    const float* __restrict__ w,
    float* __restrict__ out,
    long long n_rows,
    long long nfull)              // number of full 128-row wave-tiles
{
    __shared__ f32x4 buf[WAVES * WQ];   // 20 KiB -> 8 blocks/CU, 32 waves/CU

    const int tid  = threadIdx.x;
    const int wid  = tid >> 6;
    const int lane = tid & 63;
    f32x4* wbuf = buf + wid * WQ;

    const f32x4* __restrict__ gin  = (const f32x4*)x;
    f32x4* __restrict__       gout = (f32x4*)out;

    // cos(weights): uniform scalar loads
    float cw[NQ];
    #pragma unroll
    for (int j = 0; j < NQ; ++j) cw[j] = __cosf(w[j]);

    const long long wtile = (long long)blockIdx.x * WAVES + wid;

    if (wtile < nfull) {
        const long long base_u4 = wtile * WQ;

        // ---- stage: 5 passes, each 64 lanes x 16 B = 1 KiB contiguous ----
        #pragma unroll
        for (int p = 0; p < 5; ++p) {
            __builtin_amdgcn_global_load_lds(
                (const __attribute__((address_space(1))) void*)
                    (gin + base_u4 + p * 64 + lane),
                (__attribute__((address_space(3))) void*)(wbuf + p * 64 + lane),
                16, 0, 0);
        }
        asm volatile("s_waitcnt vmcnt(0)" ::: "memory");   // this wave's DMA only
        __builtin_amdgcn_sched_barrier(0);

        // ---- compute: lane owns row-pair 'lane' = f32x4 [5*lane .. 5*lane+4]
        float v[20];                       // static indexing -> stays in VGPRs
        f32x4* vr = (f32x4*)v;
        #pragma unroll
        for (int k = 0; k < 5; ++k) vr[k] = wbuf[lane * 5 + k];

        float pr = 1.0f;
        #pragma unroll
        for (int j = 0; j < NQ; ++j) { pr *= __cosf(v[j]) * cw[j]; v[j] = pr; }
        pr = 1.0f;
        #pragma unroll
        for (int j = 0; j < NQ; ++j) { pr *= __cosf(v[NQ + j]) * cw[j]; v[NQ + j] = pr; }

        #pragma unroll
        for (int k = 0; k < 5; ++k) wbuf[lane * 5 + k] = vr[k];

        asm volatile("s_waitcnt lgkmcnt(0)" ::: "memory"); // this wave's ds_writes
        __builtin_amdgcn_sched_barrier(0);

        // ---- store: linear re-read, 1 KiB contiguous per pass ----
        #pragma unroll
        for (int p = 0; p < 5; ++p) {
            f32x4 sv = wbuf[p * 64 + lane];
            gout[base_u4 + p * 64 + lane] = sv;
        }
    }

    // ---- generic tail (rows beyond full wave-tiles): scalar, never at bench
    // shape (4,194,304 rows = 32768 x 128 exactly). Barrier-free.
    if (blockIdx.x == 0 && wid == 0) {
        for (long long r = nfull * ROWS_PER_WAVE + lane; r < n_rows; r += 64) {
            const float* gi = x   + r * NQ;
            float*       go = out + r * NQ;
            float pr = 1.0f;
            #pragma unroll
            for (int j = 0; j < NQ; ++j) { pr *= __cosf(gi[j]) * cw[j]; go[j] = pr; }
        }
    }
}

extern "C" void kernel_launch(void* const* d_in, const int* in_sizes, int n_in,
                              void* d_out, int out_size, void* d_ws, size_t ws_size,
                              hipStream_t stream) {
    const float* x = (const float*)d_in[0];
    const float* w = (const float*)d_in[1];
    float* out = (float*)d_out;

    const long long n_elem = in_sizes[0];
    const long long n_rows = n_elem / NQ;
    const long long total_u4 = (n_rows * NQ) / 4;
    const long long nfull = total_u4 / WQ;                 // full 128-row wave-tiles
    long long blocks = (nfull + WAVES - 1) / WAVES;
    if (blocks < 1) blocks = 1;                            // tail-only degenerate case

    hipLaunchKernelGGL(qcircuit_kernel, dim3((int)blocks), dim3(BLOCK), 0, stream,
                       x, w, out, n_rows, nfull);
}